// Round 1
// baseline (855.368 us; speedup 1.0000x reference)
//
#include <hip/hip_runtime.h>

#define NPT 16384
#define MC  512
#define BATCH 8

typedef __attribute__((ext_vector_type(8))) __bf16 bf16x8;
typedef __attribute__((ext_vector_type(4))) float f32x4;

static __device__ __forceinline__ unsigned short f2bf(float f) {
    unsigned int u = __float_as_uint(f);
    unsigned int r = (u + 0x7FFFu + ((u >> 16) & 1u)) >> 16;
    return (unsigned short)r;
}

// ---------------- weight prep: fold BN scale into weights, convert to bf16 ----------
__global__ void prep_weights(const float* __restrict__ w1, const float* __restrict__ b1,
                             const float* __restrict__ s1, const float* __restrict__ t1,
                             const float* __restrict__ w2, const float* __restrict__ b2,
                             const float* __restrict__ s2, const float* __restrict__ t2,
                             const float* __restrict__ w3, const float* __restrict__ b3,
                             const float* __restrict__ s3, const float* __restrict__ t3,
                             unsigned short* __restrict__ Wp1, unsigned short* __restrict__ Wp2,
                             unsigned short* __restrict__ Wp3,
                             float* __restrict__ bias1, float* __restrict__ bias2,
                             float* __restrict__ bias3) {
    int i = blockIdx.x * blockDim.x + threadIdx.x;
    if (i < 64 * 64) {
        int o = i >> 6;
        Wp1[i] = f2bf(w1[i] * s1[o]);
    } else if (i < 64 * 64 + 128 * 64) {
        int j = i - 4096; int o = j >> 6;
        Wp2[j] = f2bf(w2[j] * s2[o]);
    } else if (i < 64 * 64 + 128 * 64 + 1024 * 128) {
        int j = i - 4096 - 8192; int o = j >> 7;
        Wp3[j] = f2bf(w3[j] * s3[o]);
    }
    if (i < 64)   bias1[i] = b1[i] * s1[i] + t1[i];
    if (i < 128)  bias2[i] = b2[i] * s2[i] + t2[i];
    if (i < 1024) bias3[i] = b3[i] * s3[i] + t3[i];
}

// ---------------- stage 1: serial scan with cycle detection ----------
__global__ __launch_bounds__(1024) void fps_kernel(const float* __restrict__ pts,
                                                   float* __restrict__ cent) {
    int b = blockIdx.x;
    const float* P = pts + (size_t)b * NPT * 3;
    float* C = cent + (size_t)b * MC * 3;
    __shared__ int hist[MC];
    __shared__ float curx, cury, curz;
    __shared__ float rd[16];
    __shared__ int ri[16];
    __shared__ int s_found, s_j;

    int tid = threadIdx.x;
    int i0 = tid * 16;
    float px[16], py[16], pz[16];
#pragma unroll
    for (int j = 0; j < 16; j++) {
        px[j] = P[(i0 + j) * 3 + 0];
        py[j] = P[(i0 + j) * 3 + 1];
        pz[j] = P[(i0 + j) * 3 + 2];
    }
    if (tid == 0) {
        hist[0] = 0;
        curx = P[0]; cury = P[1]; curz = P[2];
        C[0] = P[0]; C[1] = P[1]; C[2] = P[2];
        s_found = 0; s_j = 0;
    }
    __syncthreads();

    int t;
    for (t = 1; t < MC; t++) {
        float cx = curx, cy = cury, cz = curz;
        float bd = -1.0f; int bi = 0;
#pragma unroll
        for (int j = 0; j < 16; j++) {
            float dx = px[j] - cx, dy = py[j] - cy, dz = pz[j] - cz;
            float d2 = __fadd_rn(__fadd_rn(__fmul_rn(dx, dx), __fmul_rn(dy, dy)), __fmul_rn(dz, dz));
            float d = __fsqrt_rn(d2);
            if (d > bd) { bd = d; bi = i0 + j; }
        }
#pragma unroll
        for (int off = 32; off; off >>= 1) {
            float od = __shfl_xor(bd, off);
            int   oi = __shfl_xor(bi, off);
            if (od > bd || (od == bd && oi < bi)) { bd = od; bi = oi; }
        }
        int wid = tid >> 6;
        if ((tid & 63) == 0) { rd[wid] = bd; ri[wid] = bi; }
        __syncthreads();
        if (tid == 0) {
            float fb = rd[0]; int fi = ri[0];
            for (int wv = 1; wv < 16; wv++)
                if (rd[wv] > fb || (rd[wv] == fb && ri[wv] < fi)) { fb = rd[wv]; fi = ri[wv]; }
            int found = -1;
            for (int j = 0; j < t; j++) if (hist[j] == fi) { found = j; break; }
            hist[t] = fi;
            s_j = found;
            curx = P[fi * 3]; cury = P[fi * 3 + 1]; curz = P[fi * 3 + 2];
            C[t * 3] = curx; C[t * 3 + 1] = cury; C[t * 3 + 2] = curz;
            s_found = (found >= 0);
        }
        __syncthreads();
        if (s_found) break;
    }
    if (s_found && t < MC - 1) {
        int j = s_j, p = t - s_j;
        for (int k = t + 1 + tid; k < MC; k += 1024) {
            int src = j + (k - j) % p;
            int ind = hist[src];
            C[k * 3] = P[ind * 3]; C[k * 3 + 1] = P[ind * 3 + 1]; C[k * 3 + 2] = P[ind * 3 + 2];
        }
    }
}

// ---------------- stage 2: exact top-32 nearest + layer0 ----------
__global__ __launch_bounds__(256) void group_l0_kernel(
    const float* __restrict__ pts, const float* __restrict__ cent,
    const float* __restrict__ w0, const float* __restrict__ b0,
    const float* __restrict__ s0, const float* __restrict__ t0,
    unsigned short* __restrict__ h0) {
    int g = blockIdx.x;                // 0..4095
    int b = g >> 9;
    const float* P = pts + (size_t)b * NPT * 3;
    float cx = cent[(size_t)g * 3], cy = cent[(size_t)g * 3 + 1], cz = cent[(size_t)g * 3 + 2];

    __shared__ unsigned short key16[NPT];   // 32 KB
    __shared__ unsigned int hist[256];
    __shared__ unsigned int cand[2048];
    __shared__ int gidx[32];
    __shared__ unsigned int cnt_less, cnt_cand;
    __shared__ int sB0, sK1, sP16, sK2, sCless;
    __shared__ unsigned int lm_d[256], lm_i[256];
    __shared__ int lm_s[256];

    int tid = threadIdx.x;
    hist[tid] = 0;
    if (tid == 0) { cnt_less = 0; cnt_cand = 0; }
    __syncthreads();

    for (int i = tid; i < NPT; i += 256) {
        float dx = P[i * 3] - cx, dy = P[i * 3 + 1] - cy, dz = P[i * 3 + 2] - cz;
        float d2 = __fadd_rn(__fadd_rn(__fmul_rn(dx, dx), __fmul_rn(dy, dy)), __fmul_rn(dz, dz));
        unsigned int db = __float_as_uint(__fsqrt_rn(d2));
        key16[i] = (unsigned short)(db >> 16);
        atomicAdd(&hist[db >> 24], 1u);
    }
    __syncthreads();
    if (tid == 0) {
        unsigned int cum = 0; int bsel = 0;
        for (int v = 0; v < 256; v++) { if (cum + hist[v] >= 32u) { bsel = v; break; } cum += hist[v]; }
        sB0 = bsel; sK1 = 32 - (int)cum;
    }
    __syncthreads();
    int B0 = sB0;
    hist[tid] = 0;
    __syncthreads();
    for (int i = tid; i < NPT; i += 256) {
        unsigned short k = key16[i];
        if ((k >> 8) == B0) atomicAdd(&hist[k & 0xFF], 1u);
    }
    __syncthreads();
    if (tid == 0) {
        unsigned int cum = 0; int bsel = 0; unsigned int k1 = (unsigned int)sK1;
        for (int v = 0; v < 256; v++) { if (cum + hist[v] >= k1) { bsel = v; break; } cum += hist[v]; }
        sP16 = (B0 << 8) | bsel;
        sK2 = (int)(k1 - cum);
        sCless = 32 - sK2;
    }
    __syncthreads();
    unsigned short P16 = (unsigned short)sP16;
    for (int i = tid; i < NPT; i += 256) {
        unsigned short k = key16[i];
        if (k < P16) {
            unsigned int p = atomicAdd(&cnt_less, 1u);
            gidx[p] = i;
        } else if (k == P16) {
            unsigned int p = atomicAdd(&cnt_cand, 1u);
            if (p < 2048u) cand[p] = i;
        }
    }
    __syncthreads();
    int k2 = sK2, cless = sCless;
    unsigned int ncand = cnt_cand < 2048u ? cnt_cand : 2048u;
    for (int s = 0; s < k2; s++) {
        unsigned int bdv = 0xFFFFFFFFu, bidx = 0xFFFFFFFFu; int bslot = -1;
        for (unsigned int c = tid; c < ncand; c += 256) {
            unsigned int i = cand[c];
            if (i == 0xFFFFFFFFu) continue;
            float dx = P[i * 3] - cx, dy = P[i * 3 + 1] - cy, dz = P[i * 3 + 2] - cz;
            float d2 = __fadd_rn(__fadd_rn(__fmul_rn(dx, dx), __fmul_rn(dy, dy)), __fmul_rn(dz, dz));
            unsigned int db = __float_as_uint(__fsqrt_rn(d2));
            if (db < bdv || (db == bdv && i < bidx)) { bdv = db; bidx = i; bslot = (int)c; }
        }
        lm_d[tid] = bdv; lm_i[tid] = bidx; lm_s[tid] = bslot;
        __syncthreads();
        if (tid == 0) {
            unsigned int wd = lm_d[0], wi = lm_i[0]; int ws = lm_s[0];
            for (int q = 1; q < 256; q++)
                if (lm_d[q] < wd || (lm_d[q] == wd && lm_i[q] < wi)) { wd = lm_d[q]; wi = lm_i[q]; ws = lm_s[q]; }
            gidx[cless + s] = (int)wi;
            if (ws >= 0) cand[ws] = 0xFFFFFFFFu;
        }
        __syncthreads();
    }
    // layer 0: 3 -> 64, fp32, store bf16
    int r = tid >> 3, oq = tid & 7;
    int pi = gidx[r];
    float p0 = P[pi * 3], p1 = P[pi * 3 + 1], p2 = P[pi * 3 + 2];
    size_t row = ((size_t)g * 32 + r) * 64;
#pragma unroll
    for (int u = 0; u < 8; u++) {
        int o = oq * 8 + u;
        float y = p0 * w0[o * 3] + p1 * w0[o * 3 + 1] + p2 * w0[o * 3 + 2] + b0[o];
        float z = fmaxf(y * s0[o] + t0[o], 0.0f);
        h0[row + o] = f2bf(z);
    }
}

// ---------------- stages 3-4: bf16 MFMA GEMM + BN-relu, K=64 ----------
template <int N>
__global__ __launch_bounds__(256) void gemm_relu_kernel(
    const unsigned short* __restrict__ A, const unsigned short* __restrict__ W,
    const float* __restrict__ bias, unsigned short* __restrict__ Out) {
    int wave = threadIdx.x >> 6, lane = threadIdx.x & 63;
    int row0 = blockIdx.x * 64 + wave * 16;
    int lr = lane & 15, lq = lane >> 4;
    const int NT = N / 16;
    f32x4 acc[NT];
#pragma unroll
    for (int i = 0; i < NT; i++) acc[i] = (f32x4){0.f, 0.f, 0.f, 0.f};
#pragma unroll
    for (int ks = 0; ks < 2; ks++) {
        bf16x8 a = *(const bf16x8*)(A + ((size_t)(row0 + lr)) * 64 + ks * 32 + lq * 8);
#pragma unroll
        for (int nt = 0; nt < NT; nt++) {
            bf16x8 bfr = *(const bf16x8*)(W + ((size_t)(nt * 16 + lr)) * 64 + ks * 32 + lq * 8);
            acc[nt] = __builtin_amdgcn_mfma_f32_16x16x32_bf16(a, bfr, acc[nt], 0, 0, 0);
        }
    }
#pragma unroll
    for (int nt = 0; nt < NT; nt++) {
        int col = nt * 16 + lr;
        float bb = bias[col];
#pragma unroll
        for (int i = 0; i < 4; i++) {
            int rr = row0 + lq * 4 + i;
            float z = fmaxf(acc[nt][i] + bb, 0.0f);
            Out[(size_t)rr * N + col] = f2bf(z);
        }
    }
}

// ---------------- stage 5: GEMM 128->1024 + BN-relu + max-pool over 32 rows ----------
__global__ __launch_bounds__(256) void gemm3_max_kernel(
    const unsigned short* __restrict__ A, const unsigned short* __restrict__ W,
    const float* __restrict__ bias, float* __restrict__ Out) {
    int wave = threadIdx.x >> 6, lane = threadIdx.x & 63;
    int g = blockIdx.x >> 2, cb = blockIdx.x & 3;
    int col0 = cb * 256 + wave * 64;
    int lr = lane & 15, lq = lane >> 4;
    f32x4 acc[2][4];
#pragma unroll
    for (int r = 0; r < 2; r++)
#pragma unroll
        for (int n = 0; n < 4; n++) acc[r][n] = (f32x4){0.f, 0.f, 0.f, 0.f};
#pragma unroll
    for (int ks = 0; ks < 4; ks++) {
        bf16x8 a0 = *(const bf16x8*)(A + ((size_t)(g * 32 + lr)) * 128 + ks * 32 + lq * 8);
        bf16x8 a1 = *(const bf16x8*)(A + ((size_t)(g * 32 + 16 + lr)) * 128 + ks * 32 + lq * 8);
#pragma unroll
        for (int nt = 0; nt < 4; nt++) {
            bf16x8 bfr = *(const bf16x8*)(W + ((size_t)(col0 + nt * 16 + lr)) * 128 + ks * 32 + lq * 8);
            acc[0][nt] = __builtin_amdgcn_mfma_f32_16x16x32_bf16(a0, bfr, acc[0][nt], 0, 0, 0);
            acc[1][nt] = __builtin_amdgcn_mfma_f32_16x16x32_bf16(a1, bfr, acc[1][nt], 0, 0, 0);
        }
    }
#pragma unroll
    for (int nt = 0; nt < 4; nt++) {
        int col = col0 + nt * 16 + lr;
        float bb = bias[col];
        float m = -1e30f;
#pragma unroll
        for (int rt = 0; rt < 2; rt++)
#pragma unroll
            for (int i = 0; i < 4; i++) m = fmaxf(m, fmaxf(acc[rt][nt][i] + bb, 0.0f));
        m = fmaxf(m, __shfl_xor(m, 16));
        m = fmaxf(m, __shfl_xor(m, 32));
        if (lq == 0) Out[(size_t)g * 1024 + col] = m;
    }
}

extern "C" void kernel_launch(void* const* d_in, const int* in_sizes, int n_in,
                              void* d_out, int out_size, void* d_ws, size_t ws_size,
                              hipStream_t stream) {
    const float* points = (const float*)d_in[0];
    const float* w0 = (const float*)d_in[1];
    const float* b0 = (const float*)d_in[2];
    const float* s0 = (const float*)d_in[3];
    const float* t0 = (const float*)d_in[4];
    const float* w1 = (const float*)d_in[5];
    const float* b1 = (const float*)d_in[6];
    const float* s1 = (const float*)d_in[7];
    const float* t1 = (const float*)d_in[8];
    const float* w2 = (const float*)d_in[9];
    const float* b2 = (const float*)d_in[10];
    const float* s2 = (const float*)d_in[11];
    const float* t2 = (const float*)d_in[12];
    const float* w3 = (const float*)d_in[13];
    const float* b3 = (const float*)d_in[14];
    const float* s3 = (const float*)d_in[15];
    const float* t3 = (const float*)d_in[16];

    char* ws = (char*)d_ws;
    float* cent = (float*)(ws + 0);                      // 8*512*3*4 = 49152
    unsigned short* Wp1 = (unsigned short*)(ws + 49152);   // 8192
    unsigned short* Wp2 = (unsigned short*)(ws + 57344);   // 16384
    unsigned short* Wp3 = (unsigned short*)(ws + 73728);   // 262144
    float* bias1 = (float*)(ws + 335872);                  // 256
    float* bias2 = (float*)(ws + 336128);                  // 512
    float* bias3 = (float*)(ws + 336640);                  // 4096
    unsigned short* h0 = (unsigned short*)(ws + 340736);   // 16777216
    unsigned short* h1 = (unsigned short*)(ws + 340736 + 16777216);
    unsigned short* h2 = (unsigned short*)(ws + 340736 + 2 * 16777216);
    float* out = (float*)d_out;

    hipLaunchKernelGGL(prep_weights, dim3(560), dim3(256), 0, stream,
                       w1, b1, s1, t1, w2, b2, s2, t2, w3, b3, s3, t3,
                       Wp1, Wp2, Wp3, bias1, bias2, bias3);
    hipLaunchKernelGGL(fps_kernel, dim3(BATCH), dim3(1024), 0, stream, points, cent);
    hipLaunchKernelGGL(group_l0_kernel, dim3(4096), dim3(256), 0, stream,
                       points, cent, w0, b0, s0, t0, h0);
    hipLaunchKernelGGL((gemm_relu_kernel<64>), dim3(2048), dim3(256), 0, stream, h0, Wp1, bias1, h1);
    hipLaunchKernelGGL((gemm_relu_kernel<128>), dim3(2048), dim3(256), 0, stream, h1, Wp2, bias2, h2);
    hipLaunchKernelGGL(gemm3_max_kernel, dim3(16384), dim3(256), 0, stream, h2, Wp3, bias3, out);
}

// Round 2
// 334.672 us; speedup vs baseline: 2.5558x; 2.5558x over previous
//
#include <hip/hip_runtime.h>

#define NPT 16384
#define MC  512
#define BATCH 8
#define CAP 512

typedef __attribute__((ext_vector_type(8))) __bf16 bf16x8;
typedef __attribute__((ext_vector_type(4))) float f32x4;

static __device__ __forceinline__ unsigned short f2bf(float f) {
    unsigned int u = __float_as_uint(f);
    unsigned int r = (u + 0x7FFFu + ((u >> 16) & 1u)) >> 16;
    return (unsigned short)r;
}

// ---------------- weight prep: fold BN scale into weights, convert to bf16 ----------
__global__ void prep_weights(const float* __restrict__ w1, const float* __restrict__ b1,
                             const float* __restrict__ s1, const float* __restrict__ t1,
                             const float* __restrict__ w2, const float* __restrict__ b2,
                             const float* __restrict__ s2, const float* __restrict__ t2,
                             const float* __restrict__ w3, const float* __restrict__ b3,
                             const float* __restrict__ s3, const float* __restrict__ t3,
                             unsigned short* __restrict__ Wp1, unsigned short* __restrict__ Wp2,
                             unsigned short* __restrict__ Wp3,
                             float* __restrict__ bias1, float* __restrict__ bias2,
                             float* __restrict__ bias3) {
    int i = blockIdx.x * blockDim.x + threadIdx.x;
    if (i < 64 * 64) {
        int o = i >> 6;
        Wp1[i] = f2bf(w1[i] * s1[o]);
    } else if (i < 64 * 64 + 128 * 64) {
        int j = i - 4096; int o = j >> 6;
        Wp2[j] = f2bf(w2[j] * s2[o]);
    } else if (i < 64 * 64 + 128 * 64 + 1024 * 128) {
        int j = i - 4096 - 8192; int o = j >> 7;
        Wp3[j] = f2bf(w3[j] * s3[o]);
    }
    if (i < 64)   bias1[i] = b1[i] * s1[i] + t1[i];
    if (i < 128)  bias2[i] = b2[i] * s2[i] + t2[i];
    if (i < 1024) bias3[i] = b3[i] * s3[i] + t3[i];
}

// ---------------- stage 1: serial scan with cycle detection ----------
__global__ __launch_bounds__(1024) void fps_kernel(const float* __restrict__ pts,
                                                   float* __restrict__ cent) {
    int b = blockIdx.x;
    const float* P = pts + (size_t)b * NPT * 3;
    float* C = cent + (size_t)b * MC * 3;
    __shared__ int hist[MC];
    __shared__ float curx, cury, curz;
    __shared__ float rd[16];
    __shared__ int ri[16];
    __shared__ int s_found, s_j;

    int tid = threadIdx.x;
    int i0 = tid * 16;
    float px[16], py[16], pz[16];
#pragma unroll
    for (int j = 0; j < 16; j++) {
        px[j] = P[(i0 + j) * 3 + 0];
        py[j] = P[(i0 + j) * 3 + 1];
        pz[j] = P[(i0 + j) * 3 + 2];
    }
    if (tid == 0) {
        hist[0] = 0;
        curx = P[0]; cury = P[1]; curz = P[2];
        C[0] = P[0]; C[1] = P[1]; C[2] = P[2];
        s_found = 0; s_j = 0;
    }
    __syncthreads();

    int t;
    for (t = 1; t < MC; t++) {
        float cx = curx, cy = cury, cz = curz;
        float bd = -1.0f; int bi = 0;
#pragma unroll
        for (int j = 0; j < 16; j++) {
            float dx = px[j] - cx, dy = py[j] - cy, dz = pz[j] - cz;
            float d2 = __fadd_rn(__fadd_rn(__fmul_rn(dx, dx), __fmul_rn(dy, dy)), __fmul_rn(dz, dz));
            float d = __fsqrt_rn(d2);
            if (d > bd) { bd = d; bi = i0 + j; }
        }
#pragma unroll
        for (int off = 32; off; off >>= 1) {
            float od = __shfl_xor(bd, off);
            int   oi = __shfl_xor(bi, off);
            if (od > bd || (od == bd && oi < bi)) { bd = od; bi = oi; }
        }
        int wid = tid >> 6;
        if ((tid & 63) == 0) { rd[wid] = bd; ri[wid] = bi; }
        __syncthreads();
        if (tid == 0) {
            float fb = rd[0]; int fi = ri[0];
            for (int wv = 1; wv < 16; wv++)
                if (rd[wv] > fb || (rd[wv] == fb && ri[wv] < fi)) { fb = rd[wv]; fi = ri[wv]; }
            int found = -1;
            for (int j = 0; j < t; j++) if (hist[j] == fi) { found = j; break; }
            hist[t] = fi;
            s_j = found;
            curx = P[fi * 3]; cury = P[fi * 3 + 1]; curz = P[fi * 3 + 2];
            C[t * 3] = curx; C[t * 3 + 1] = cury; C[t * 3 + 2] = curz;
            s_found = (found >= 0);
        }
        __syncthreads();
        if (s_found) break;
    }
    if (s_found && t < MC - 1) {
        int j = s_j, p = t - s_j;
        for (int k = t + 1 + tid; k < MC; k += 1024) {
            int src = j + (k - j) % p;
            int ind = hist[src];
            C[k * 3] = P[ind * 3]; C[k * 3 + 1] = P[ind * 3 + 1]; C[k * 3 + 2] = P[ind * 3 + 2];
        }
    }
}

// ---------------- stage 2: exact top-32 via lane-min bound + gather, then layer0 ----------
// one wave per centroid; 4 waves per block
__global__ __launch_bounds__(256) void group_l0_kernel(
    const float* __restrict__ pts, const float* __restrict__ cent,
    const float* __restrict__ w0, const float* __restrict__ b0,
    const float* __restrict__ s0, const float* __restrict__ t0,
    unsigned short* __restrict__ h0) {
    int wv = threadIdx.x >> 6, lane = threadIdx.x & 63;
    int g = blockIdx.x * 4 + wv;          // 0..4095
    int b = g >> 9;
    const float* P = pts + (size_t)b * NPT * 3;
    float cx = cent[(size_t)g * 3], cy = cent[(size_t)g * 3 + 1], cz = cent[(size_t)g * 3 + 2];

    __shared__ unsigned long long cand[4][CAP];
    __shared__ int scnt[4];
    __shared__ float sxyz[4][32][3];

    if (lane == 0) scnt[wv] = 0;
    __syncthreads();

    // pass 1: per-lane min distance over its 256-point slice
    unsigned int lmin = 0xFFFFFFFFu;
#pragma unroll 4
    for (int i = lane; i < NPT; i += 64) {
        float px = P[i * 3], py = P[i * 3 + 1], pz = P[i * 3 + 2];
        float dx = px - cx, dy = py - cy, dz = pz - cz;
        float d2 = __fadd_rn(__fadd_rn(__fmul_rn(dx, dx), __fmul_rn(dy, dy)), __fmul_rn(dz, dz));
        unsigned int db = __float_as_uint(__fsqrt_rn(d2));
        lmin = lmin < db ? lmin : db;
    }
    // bitonic sort of 64 lane minima (ascending); B = 32nd smallest => upper bound on true d32
    unsigned int v = lmin;
#pragma unroll
    for (int k = 2; k <= 64; k <<= 1) {
#pragma unroll
        for (int j = k >> 1; j > 0; j >>= 1) {
            unsigned int o = __shfl_xor(v, j);
            bool lower = (lane & j) == 0;
            bool asc = (lane & k) == 0;
            unsigned int mn = o < v ? o : v;
            unsigned int mx = o < v ? v : o;
            v = (lower == asc) ? mn : mx;
        }
    }
    unsigned int B = __shfl(v, 31);

    // pass 2: gather candidates with d <= B
#pragma unroll 4
    for (int i = lane; i < NPT; i += 64) {
        float px = P[i * 3], py = P[i * 3 + 1], pz = P[i * 3 + 2];
        float dx = px - cx, dy = py - cy, dz = pz - cz;
        float d2 = __fadd_rn(__fadd_rn(__fmul_rn(dx, dx), __fmul_rn(dy, dy)), __fmul_rn(dz, dz));
        unsigned int db = __float_as_uint(__fsqrt_rn(d2));
        if (db <= B) {
            int p = atomicAdd(&scnt[wv], 1);
            if (p < CAP) cand[wv][p] = ((unsigned long long)db << 32) | (unsigned int)i;
        }
    }
    __syncthreads();
    int n = scnt[wv];

    // exact top-32 by (dbits, idx) lex order (matches top_k tie-break: lowest index)
    unsigned long long sel = 0;
    unsigned long long last = 0;
    if (n <= CAP) {
        for (int s = 0; s < 32; s++) {
            unsigned long long best = ~0ull;
            for (int c = lane; c < n; c += 64) {
                unsigned long long kk = cand[wv][c];
                if ((s == 0 || kk > last) && kk < best) best = kk;
            }
#pragma unroll
            for (int off = 32; off; off >>= 1) {
                unsigned long long o = __shfl_xor(best, off);
                best = o < best ? o : best;
            }
            last = best;
            if (lane == s) sel = best;
        }
    } else {
        // exact streaming fallback (never expected; correctness insurance)
        for (int s = 0; s < 32; s++) {
            unsigned long long best = ~0ull;
            for (int i = lane; i < NPT; i += 64) {
                float px = P[i * 3], py = P[i * 3 + 1], pz = P[i * 3 + 2];
                float dx = px - cx, dy = py - cy, dz = pz - cz;
                float d2 = __fadd_rn(__fadd_rn(__fmul_rn(dx, dx), __fmul_rn(dy, dy)), __fmul_rn(dz, dz));
                unsigned int db = __float_as_uint(__fsqrt_rn(d2));
                unsigned long long kk = ((unsigned long long)db << 32) | (unsigned int)i;
                if ((s == 0 || kk > last) && kk < best) best = kk;
            }
#pragma unroll
            for (int off = 32; off; off >>= 1) {
                unsigned long long o = __shfl_xor(best, off);
                best = o < best ? o : best;
            }
            last = best;
            if (lane == s) sel = best;
        }
    }
    if (lane < 32) {
        unsigned int idx = (unsigned int)sel;
        sxyz[wv][lane][0] = P[idx * 3];
        sxyz[wv][lane][1] = P[idx * 3 + 1];
        sxyz[wv][lane][2] = P[idx * 3 + 2];
    }
    __syncthreads();

    // layer 0: 3 -> 64, one output column per lane, rows = 32 selected points
    int o = lane;
    float sw = s0[o];
    float fw0 = w0[o * 3] * sw, fw1 = w0[o * 3 + 1] * sw, fw2 = w0[o * 3 + 2] * sw;
    float fb = b0[o] * sw + t0[o];
    size_t base = (size_t)g * 32 * 64 + o;
#pragma unroll 8
    for (int r = 0; r < 32; r++) {
        float x = sxyz[wv][r][0], y = sxyz[wv][r][1], z = sxyz[wv][r][2];
        float acc = fmaf(z, fw2, fmaf(y, fw1, fmaf(x, fw0, fb)));
        h0[base + (size_t)r * 64] = f2bf(fmaxf(acc, 0.0f));
    }
}

// ---------------- stages 3-4: bf16 MFMA GEMM + BN-relu, K=64 ----------
template <int N>
__global__ __launch_bounds__(256) void gemm_relu_kernel(
    const unsigned short* __restrict__ A, const unsigned short* __restrict__ W,
    const float* __restrict__ bias, unsigned short* __restrict__ Out) {
    int wave = threadIdx.x >> 6, lane = threadIdx.x & 63;
    int row0 = blockIdx.x * 64 + wave * 16;
    int lr = lane & 15, lq = lane >> 4;
    const int NT = N / 16;
    f32x4 acc[NT];
#pragma unroll
    for (int i = 0; i < NT; i++) acc[i] = (f32x4){0.f, 0.f, 0.f, 0.f};
#pragma unroll
    for (int ks = 0; ks < 2; ks++) {
        bf16x8 a = *(const bf16x8*)(A + ((size_t)(row0 + lr)) * 64 + ks * 32 + lq * 8);
#pragma unroll
        for (int nt = 0; nt < NT; nt++) {
            bf16x8 bfr = *(const bf16x8*)(W + ((size_t)(nt * 16 + lr)) * 64 + ks * 32 + lq * 8);
            acc[nt] = __builtin_amdgcn_mfma_f32_16x16x32_bf16(a, bfr, acc[nt], 0, 0, 0);
        }
    }
#pragma unroll
    for (int nt = 0; nt < NT; nt++) {
        int col = nt * 16 + lr;
        float bb = bias[col];
#pragma unroll
        for (int i = 0; i < 4; i++) {
            int rr = row0 + lq * 4 + i;
            float z = fmaxf(acc[nt][i] + bb, 0.0f);
            Out[(size_t)rr * N + col] = f2bf(z);
        }
    }
}

// ---------------- stage 5: GEMM 128->1024 + BN-relu + max-pool over 32 rows ----------
__global__ __launch_bounds__(256) void gemm3_max_kernel(
    const unsigned short* __restrict__ A, const unsigned short* __restrict__ W,
    const float* __restrict__ bias, float* __restrict__ Out) {
    int wave = threadIdx.x >> 6, lane = threadIdx.x & 63;
    int g = blockIdx.x >> 2, cb = blockIdx.x & 3;
    int col0 = cb * 256 + wave * 64;
    int lr = lane & 15, lq = lane >> 4;
    f32x4 acc[2][4];
#pragma unroll
    for (int r = 0; r < 2; r++)
#pragma unroll
        for (int n = 0; n < 4; n++) acc[r][n] = (f32x4){0.f, 0.f, 0.f, 0.f};
#pragma unroll
    for (int ks = 0; ks < 4; ks++) {
        bf16x8 a0 = *(const bf16x8*)(A + ((size_t)(g * 32 + lr)) * 128 + ks * 32 + lq * 8);
        bf16x8 a1 = *(const bf16x8*)(A + ((size_t)(g * 32 + 16 + lr)) * 128 + ks * 32 + lq * 8);
#pragma unroll
        for (int nt = 0; nt < 4; nt++) {
            bf16x8 bfr = *(const bf16x8*)(W + ((size_t)(col0 + nt * 16 + lr)) * 128 + ks * 32 + lq * 8);
            acc[0][nt] = __builtin_amdgcn_mfma_f32_16x16x32_bf16(a0, bfr, acc[0][nt], 0, 0, 0);
            acc[1][nt] = __builtin_amdgcn_mfma_f32_16x16x32_bf16(a1, bfr, acc[1][nt], 0, 0, 0);
        }
    }
#pragma unroll
    for (int nt = 0; nt < 4; nt++) {
        int col = col0 + nt * 16 + lr;
        float bb = bias[col];
        float m = -1e30f;
#pragma unroll
        for (int rt = 0; rt < 2; rt++)
#pragma unroll
            for (int i = 0; i < 4; i++) m = fmaxf(m, fmaxf(acc[rt][nt][i] + bb, 0.0f));
        m = fmaxf(m, __shfl_xor(m, 16));
        m = fmaxf(m, __shfl_xor(m, 32));
        if (lq == 0) Out[(size_t)g * 1024 + col] = m;
    }
}

extern "C" void kernel_launch(void* const* d_in, const int* in_sizes, int n_in,
                              void* d_out, int out_size, void* d_ws, size_t ws_size,
                              hipStream_t stream) {
    const float* points = (const float*)d_in[0];
    const float* w0 = (const float*)d_in[1];
    const float* b0 = (const float*)d_in[2];
    const float* s0 = (const float*)d_in[3];
    const float* t0 = (const float*)d_in[4];
    const float* w1 = (const float*)d_in[5];
    const float* b1 = (const float*)d_in[6];
    const float* s1 = (const float*)d_in[7];
    const float* t1 = (const float*)d_in[8];
    const float* w2 = (const float*)d_in[9];
    const float* b2 = (const float*)d_in[10];
    const float* s2 = (const float*)d_in[11];
    const float* t2 = (const float*)d_in[12];
    const float* w3 = (const float*)d_in[13];
    const float* b3 = (const float*)d_in[14];
    const float* s3 = (const float*)d_in[15];
    const float* t3 = (const float*)d_in[16];

    char* ws = (char*)d_ws;
    float* cent = (float*)(ws + 0);                      // 8*512*3*4 = 49152
    unsigned short* Wp1 = (unsigned short*)(ws + 49152);   // 8192
    unsigned short* Wp2 = (unsigned short*)(ws + 57344);   // 16384
    unsigned short* Wp3 = (unsigned short*)(ws + 73728);   // 262144
    float* bias1 = (float*)(ws + 335872);                  // 256
    float* bias2 = (float*)(ws + 336128);                  // 512
    float* bias3 = (float*)(ws + 336640);                  // 4096
    unsigned short* h0 = (unsigned short*)(ws + 340736);   // 16777216
    unsigned short* h1 = (unsigned short*)(ws + 340736 + 16777216);
    unsigned short* h2 = (unsigned short*)(ws + 340736 + 2 * 16777216);
    float* out = (float*)d_out;

    hipLaunchKernelGGL(prep_weights, dim3(560), dim3(256), 0, stream,
                       w1, b1, s1, t1, w2, b2, s2, t2, w3, b3, s3, t3,
                       Wp1, Wp2, Wp3, bias1, bias2, bias3);
    hipLaunchKernelGGL(fps_kernel, dim3(BATCH), dim3(1024), 0, stream, points, cent);
    hipLaunchKernelGGL(group_l0_kernel, dim3(1024), dim3(256), 0, stream,
                       points, cent, w0, b0, s0, t0, h0);
    hipLaunchKernelGGL((gemm_relu_kernel<64>), dim3(2048), dim3(256), 0, stream, h0, Wp1, bias1, h1);
    hipLaunchKernelGGL((gemm_relu_kernel<128>), dim3(2048), dim3(256), 0, stream, h1, Wp2, bias2, h2);
    hipLaunchKernelGGL(gemm3_max_kernel, dim3(16384), dim3(256), 0, stream, h2, Wp3, bias3, out);
}

// Round 3
// 233.438 us; speedup vs baseline: 3.6642x; 1.4337x over previous
//
#include <hip/hip_runtime.h>

#define NPT 16384
#define MC  512
#define BATCH 8
#define CAP 512

typedef __attribute__((ext_vector_type(8))) __bf16 bf16x8;
typedef __attribute__((ext_vector_type(4))) float f32x4;

static __device__ __forceinline__ unsigned short f2bf(float f) {
    unsigned int u = __float_as_uint(f);
    unsigned int r = (u + 0x7FFFu + ((u >> 16) & 1u)) >> 16;
    return (unsigned short)r;
}

// ---------------- weight prep: fold BN scale into weights, convert to bf16 ----------
__global__ void prep_weights(const float* __restrict__ w1, const float* __restrict__ b1,
                             const float* __restrict__ s1, const float* __restrict__ t1,
                             const float* __restrict__ w2, const float* __restrict__ b2,
                             const float* __restrict__ s2, const float* __restrict__ t2,
                             const float* __restrict__ w3, const float* __restrict__ b3,
                             const float* __restrict__ s3, const float* __restrict__ t3,
                             unsigned short* __restrict__ Wp1, unsigned short* __restrict__ Wp2,
                             unsigned short* __restrict__ Wp3,
                             float* __restrict__ bias1, float* __restrict__ bias2,
                             float* __restrict__ bias3) {
    int i = blockIdx.x * blockDim.x + threadIdx.x;
    if (i < 64 * 64) {
        int o = i >> 6;
        Wp1[i] = f2bf(w1[i] * s1[o]);
    } else if (i < 64 * 64 + 128 * 64) {
        int j = i - 4096; int o = j >> 6;
        Wp2[j] = f2bf(w2[j] * s2[o]);
    } else if (i < 64 * 64 + 128 * 64 + 1024 * 128) {
        int j = i - 4096 - 8192; int o = j >> 7;
        Wp3[j] = f2bf(w3[j] * s3[o]);
    }
    if (i < 64)   bias1[i] = b1[i] * s1[i] + t1[i];
    if (i < 128)  bias2[i] = b2[i] * s2[i] + t2[i];
    if (i < 1024) bias3[i] = b3[i] * s3[i] + t3[i];
}

// ---------------- stage 1: serial scan with cycle detection ----------
__global__ __launch_bounds__(1024) void fps_kernel(const float* __restrict__ pts,
                                                   float* __restrict__ cent) {
    int b = blockIdx.x;
    const float* P = pts + (size_t)b * NPT * 3;
    float* C = cent + (size_t)b * MC * 3;
    __shared__ int hist[MC];
    __shared__ float curx, cury, curz;
    __shared__ float rd[16];
    __shared__ int ri[16];
    __shared__ int s_found, s_j;

    int tid = threadIdx.x;
    int i0 = tid * 16;
    float px[16], py[16], pz[16];
#pragma unroll
    for (int j = 0; j < 16; j++) {
        px[j] = P[(i0 + j) * 3 + 0];
        py[j] = P[(i0 + j) * 3 + 1];
        pz[j] = P[(i0 + j) * 3 + 2];
    }
    if (tid == 0) {
        hist[0] = 0;
        curx = P[0]; cury = P[1]; curz = P[2];
        C[0] = P[0]; C[1] = P[1]; C[2] = P[2];
        s_found = 0; s_j = 0;
    }
    __syncthreads();

    int t;
    for (t = 1; t < MC; t++) {
        float cx = curx, cy = cury, cz = curz;
        float bd = -1.0f; int bi = 0;
#pragma unroll
        for (int j = 0; j < 16; j++) {
            float dx = px[j] - cx, dy = py[j] - cy, dz = pz[j] - cz;
            float d2 = __fadd_rn(__fadd_rn(__fmul_rn(dx, dx), __fmul_rn(dy, dy)), __fmul_rn(dz, dz));
            float d = __fsqrt_rn(d2);
            if (d > bd) { bd = d; bi = i0 + j; }
        }
#pragma unroll
        for (int off = 32; off; off >>= 1) {
            float od = __shfl_xor(bd, off);
            int   oi = __shfl_xor(bi, off);
            if (od > bd || (od == bd && oi < bi)) { bd = od; bi = oi; }
        }
        int wid = tid >> 6;
        if ((tid & 63) == 0) { rd[wid] = bd; ri[wid] = bi; }
        __syncthreads();
        if (tid == 0) {
            float fb = rd[0]; int fi = ri[0];
            for (int wv = 1; wv < 16; wv++)
                if (rd[wv] > fb || (rd[wv] == fb && ri[wv] < fi)) { fb = rd[wv]; fi = ri[wv]; }
            int found = -1;
            for (int j = 0; j < t; j++) if (hist[j] == fi) { found = j; break; }
            hist[t] = fi;
            s_j = found;
            curx = P[fi * 3]; cury = P[fi * 3 + 1]; curz = P[fi * 3 + 2];
            C[t * 3] = curx; C[t * 3 + 1] = cury; C[t * 3 + 2] = curz;
            s_found = (found >= 0);
        }
        __syncthreads();
        if (s_found) break;
    }
    if (s_found && t < MC - 1) {
        int j = s_j, p = t - s_j;
        for (int k = t + 1 + tid; k < MC; k += 1024) {
            int src = j + (k - j) % p;
            int ind = hist[src];
            C[k * 3] = P[ind * 3]; C[k * 3 + 1] = P[ind * 3 + 1]; C[k * 3 + 2] = P[ind * 3 + 2];
        }
    }
}

// ---------------- stage 2: exact top-32 via lane-min bound + gather, then layer0 ----------
__global__ __launch_bounds__(256) void group_l0_kernel(
    const float* __restrict__ pts, const float* __restrict__ cent,
    const float* __restrict__ w0, const float* __restrict__ b0,
    const float* __restrict__ s0, const float* __restrict__ t0,
    unsigned short* __restrict__ h0) {
    int wv = threadIdx.x >> 6, lane = threadIdx.x & 63;
    int g = blockIdx.x * 4 + wv;          // 0..4095
    int b = g >> 9;
    const float* P = pts + (size_t)b * NPT * 3;
    float cx = cent[(size_t)g * 3], cy = cent[(size_t)g * 3 + 1], cz = cent[(size_t)g * 3 + 2];

    __shared__ unsigned long long cand[4][CAP];
    __shared__ int scnt[4];
    __shared__ float sxyz[4][32][3];

    if (lane == 0) scnt[wv] = 0;
    __syncthreads();

    unsigned int lmin = 0xFFFFFFFFu;
#pragma unroll 4
    for (int i = lane; i < NPT; i += 64) {
        float px = P[i * 3], py = P[i * 3 + 1], pz = P[i * 3 + 2];
        float dx = px - cx, dy = py - cy, dz = pz - cz;
        float d2 = __fadd_rn(__fadd_rn(__fmul_rn(dx, dx), __fmul_rn(dy, dy)), __fmul_rn(dz, dz));
        unsigned int db = __float_as_uint(__fsqrt_rn(d2));
        lmin = lmin < db ? lmin : db;
    }
    unsigned int v = lmin;
#pragma unroll
    for (int k = 2; k <= 64; k <<= 1) {
#pragma unroll
        for (int j = k >> 1; j > 0; j >>= 1) {
            unsigned int o = __shfl_xor(v, j);
            bool lower = (lane & j) == 0;
            bool asc = (lane & k) == 0;
            unsigned int mn = o < v ? o : v;
            unsigned int mx = o < v ? v : o;
            v = (lower == asc) ? mn : mx;
        }
    }
    unsigned int B = __shfl(v, 31);

#pragma unroll 4
    for (int i = lane; i < NPT; i += 64) {
        float px = P[i * 3], py = P[i * 3 + 1], pz = P[i * 3 + 2];
        float dx = px - cx, dy = py - cy, dz = pz - cz;
        float d2 = __fadd_rn(__fadd_rn(__fmul_rn(dx, dx), __fmul_rn(dy, dy)), __fmul_rn(dz, dz));
        unsigned int db = __float_as_uint(__fsqrt_rn(d2));
        if (db <= B) {
            int p = atomicAdd(&scnt[wv], 1);
            if (p < CAP) cand[wv][p] = ((unsigned long long)db << 32) | (unsigned int)i;
        }
    }
    __syncthreads();
    int n = scnt[wv];

    unsigned long long sel = 0;
    unsigned long long last = 0;
    if (n <= CAP) {
        for (int s = 0; s < 32; s++) {
            unsigned long long best = ~0ull;
            for (int c = lane; c < n; c += 64) {
                unsigned long long kk = cand[wv][c];
                if ((s == 0 || kk > last) && kk < best) best = kk;
            }
#pragma unroll
            for (int off = 32; off; off >>= 1) {
                unsigned long long o = __shfl_xor(best, off);
                best = o < best ? o : best;
            }
            last = best;
            if (lane == s) sel = best;
        }
    } else {
        for (int s = 0; s < 32; s++) {
            unsigned long long best = ~0ull;
            for (int i = lane; i < NPT; i += 64) {
                float px = P[i * 3], py = P[i * 3 + 1], pz = P[i * 3 + 2];
                float dx = px - cx, dy = py - cy, dz = pz - cz;
                float d2 = __fadd_rn(__fadd_rn(__fmul_rn(dx, dx), __fmul_rn(dy, dy)), __fmul_rn(dz, dz));
                unsigned int db = __float_as_uint(__fsqrt_rn(d2));
                unsigned long long kk = ((unsigned long long)db << 32) | (unsigned int)i;
                if ((s == 0 || kk > last) && kk < best) best = kk;
            }
#pragma unroll
            for (int off = 32; off; off >>= 1) {
                unsigned long long o = __shfl_xor(best, off);
                best = o < best ? o : best;
            }
            last = best;
            if (lane == s) sel = best;
        }
    }
    if (lane < 32) {
        unsigned int idx = (unsigned int)sel;
        sxyz[wv][lane][0] = P[idx * 3];
        sxyz[wv][lane][1] = P[idx * 3 + 1];
        sxyz[wv][lane][2] = P[idx * 3 + 2];
    }
    __syncthreads();

    int o = lane;
    float sw = s0[o];
    float fw0 = w0[o * 3] * sw, fw1 = w0[o * 3 + 1] * sw, fw2 = w0[o * 3 + 2] * sw;
    float fb = b0[o] * sw + t0[o];
    size_t base = (size_t)g * 32 * 64 + o;
#pragma unroll 8
    for (int r = 0; r < 32; r++) {
        float x = sxyz[wv][r][0], y = sxyz[wv][r][1], z = sxyz[wv][r][2];
        float acc = fmaf(z, fw2, fmaf(y, fw1, fmaf(x, fw0, fb)));
        h0[base + (size_t)r * 64] = f2bf(fmaxf(acc, 0.0f));
    }
}

// ---------------- stages 3-4: W staged in swizzled LDS, 256 rows/block ----------
// W rows are 64 bf16 = 128 B = 8 16B-slots; LDS[r][s] = W[r][s^(r&7)] kills the
// stride-128B full-wave bank collision on ds_read_b128 (16 lanes -> 8 slots, 2-way = free).
template <int N>
__global__ __launch_bounds__(256) void gemm_relu_kernel(
    const unsigned short* __restrict__ A, const unsigned short* __restrict__ W,
    const float* __restrict__ bias, unsigned short* __restrict__ Out) {
    __shared__ unsigned short sW[N * 64];
    int tid = threadIdx.x, w = tid >> 6, lane = tid & 63, lr = lane & 15, lq = lane >> 4;
    const int SWEEPS = (N * 64 * 2) / 4096;
#pragma unroll
    for (int sweep = 0; sweep < SWEEPS; ++sweep) {
        int r = sweep * 32 + (tid >> 3), s = tid & 7;
        int ss = s ^ (r & 7);
        *(uint4*)&sW[r * 64 + s * 8] = *(const uint4*)&W[r * 64 + ss * 8];
    }
    __syncthreads();

    int row0 = blockIdx.x * 256 + w * 64;
    const int NT = N / 16;
    f32x4 acc[4][NT];
#pragma unroll
    for (int m = 0; m < 4; m++)
#pragma unroll
        for (int n = 0; n < NT; n++) acc[m][n] = (f32x4){0.f, 0.f, 0.f, 0.f};

    bf16x8 a[4][2];
#pragma unroll
    for (int m = 0; m < 4; m++)
#pragma unroll
        for (int ks = 0; ks < 2; ks++)
            a[m][ks] = *(const bf16x8*)&A[(size_t)(row0 + m * 16 + lr) * 64 + ks * 32 + lq * 8];

#pragma unroll
    for (int ks = 0; ks < 2; ks++)
#pragma unroll
        for (int n = 0; n < NT; n++) {
            bf16x8 wf = *(const bf16x8*)&sW[(n * 16 + lr) * 64 + (((ks * 4 + lq) ^ (lr & 7)) * 8)];
#pragma unroll
            for (int m = 0; m < 4; m++)
                acc[m][n] = __builtin_amdgcn_mfma_f32_16x16x32_bf16(a[m][ks], wf, acc[m][n], 0, 0, 0);
        }

#pragma unroll
    for (int n = 0; n < NT; n++) {
        int col = n * 16 + lr;
        float bb = bias[col];
#pragma unroll
        for (int m = 0; m < 4; m++)
#pragma unroll
            for (int i = 0; i < 4; i++) {
                int rr = row0 + m * 16 + lq * 4 + i;
                Out[(size_t)rr * N + col] = f2bf(fmaxf(acc[m][n][i] + bb, 0.f));
            }
    }
}

// ---------------- stage 5: A in registers, loop col-blocks, W-tile in swizzled LDS ----------
// block = 4 waves (2m x 2n), 128 rows; A frags held in VGPRs across all 4 col-blocks
// -> A read from HBM exactly once; W (256 KB) stays L2-resident across blocks.
__global__ __launch_bounds__(256) void gemm3_max_kernel(
    const unsigned short* __restrict__ A, const unsigned short* __restrict__ W,
    const float* __restrict__ bias, float* __restrict__ Out) {
    __shared__ unsigned short sW[256 * 128];   // 64 KB, swizzled
    int tid = threadIdx.x, w = tid >> 6, lane = tid & 63, lr = lane & 15, lq = lane >> 4;
    int row0 = blockIdx.x * 128 + (w >> 1) * 64;
    int ch = w & 1;
    int g0 = row0 >> 5;

    bf16x8 a[4][4];
#pragma unroll
    for (int m = 0; m < 4; m++)
#pragma unroll
        for (int ks = 0; ks < 4; ks++)
            a[m][ks] = *(const bf16x8*)&A[(size_t)(row0 + m * 16 + lr) * 128 + ks * 32 + lq * 8];

    for (int cb = 0; cb < 4; ++cb) {
        // stage W rows [cb*256, cb*256+256), 256B rows = 16 slots, swizzled
#pragma unroll
        for (int sweep = 0; sweep < 16; ++sweep) {
            int r = sweep * 16 + (tid >> 4), s = tid & 15;
            int ss = s ^ (r & 7);
            *(uint4*)&sW[r * 128 + s * 8] = *(const uint4*)&W[(size_t)(cb * 256 + r) * 128 + ss * 8];
        }
        __syncthreads();

        f32x4 acc[4][8];
#pragma unroll
        for (int m = 0; m < 4; m++)
#pragma unroll
            for (int n = 0; n < 8; n++) acc[m][n] = (f32x4){0.f, 0.f, 0.f, 0.f};

#pragma unroll
        for (int ks = 0; ks < 4; ks++)
#pragma unroll
            for (int n = 0; n < 8; n++) {
                int rw = ch * 128 + n * 16 + lr;
                bf16x8 wf = *(const bf16x8*)&sW[rw * 128 + (((ks * 4 + lq) ^ (lr & 7)) * 8)];
#pragma unroll
                for (int m = 0; m < 4; m++)
                    acc[m][n] = __builtin_amdgcn_mfma_f32_16x16x32_bf16(a[m][ks], wf, acc[m][n], 0, 0, 0);
            }

#pragma unroll
        for (int n = 0; n < 8; n++) {
            int col = cb * 256 + ch * 128 + n * 16 + lr;
            float bb = bias[col];
            float v0 = 0.f, v1 = 0.f;
#pragma unroll
            for (int i = 0; i < 4; i++) {
                v0 = fmaxf(v0, fmaxf(acc[0][n][i] + bb, 0.f));
                v0 = fmaxf(v0, fmaxf(acc[1][n][i] + bb, 0.f));
                v1 = fmaxf(v1, fmaxf(acc[2][n][i] + bb, 0.f));
                v1 = fmaxf(v1, fmaxf(acc[3][n][i] + bb, 0.f));
            }
            v0 = fmaxf(v0, __shfl_xor(v0, 16)); v0 = fmaxf(v0, __shfl_xor(v0, 32));
            v1 = fmaxf(v1, __shfl_xor(v1, 16)); v1 = fmaxf(v1, __shfl_xor(v1, 32));
            if (lq == 0) {
                Out[(size_t)g0 * 1024 + col] = v0;
                Out[(size_t)(g0 + 1) * 1024 + col] = v1;
            }
        }
        __syncthreads();
    }
}

extern "C" void kernel_launch(void* const* d_in, const int* in_sizes, int n_in,
                              void* d_out, int out_size, void* d_ws, size_t ws_size,
                              hipStream_t stream) {
    const float* points = (const float*)d_in[0];
    const float* w0 = (const float*)d_in[1];
    const float* b0 = (const float*)d_in[2];
    const float* s0 = (const float*)d_in[3];
    const float* t0 = (const float*)d_in[4];
    const float* w1 = (const float*)d_in[5];
    const float* b1 = (const float*)d_in[6];
    const float* s1 = (const float*)d_in[7];
    const float* t1 = (const float*)d_in[8];
    const float* w2 = (const float*)d_in[9];
    const float* b2 = (const float*)d_in[10];
    const float* s2 = (const float*)d_in[11];
    const float* t2 = (const float*)d_in[12];
    const float* w3 = (const float*)d_in[13];
    const float* b3 = (const float*)d_in[14];
    const float* s3 = (const float*)d_in[15];
    const float* t3 = (const float*)d_in[16];

    char* ws = (char*)d_ws;
    float* cent = (float*)(ws + 0);                        // 49152
    unsigned short* Wp1 = (unsigned short*)(ws + 49152);   // 8192
    unsigned short* Wp2 = (unsigned short*)(ws + 57344);   // 16384
    unsigned short* Wp3 = (unsigned short*)(ws + 73728);   // 262144
    float* bias1 = (float*)(ws + 335872);
    float* bias2 = (float*)(ws + 336128);
    float* bias3 = (float*)(ws + 336640);
    unsigned short* h0 = (unsigned short*)(ws + 340736);   // 16 MB
    unsigned short* h1 = (unsigned short*)(ws + 340736 + 16777216);
    unsigned short* h2 = (unsigned short*)(ws + 340736 + 2 * 16777216);
    float* out = (float*)d_out;

    hipLaunchKernelGGL(prep_weights, dim3(560), dim3(256), 0, stream,
                       w1, b1, s1, t1, w2, b2, s2, t2, w3, b3, s3, t3,
                       Wp1, Wp2, Wp3, bias1, bias2, bias3);
    hipLaunchKernelGGL(fps_kernel, dim3(BATCH), dim3(1024), 0, stream, points, cent);
    hipLaunchKernelGGL(group_l0_kernel, dim3(1024), dim3(256), 0, stream,
                       points, cent, w0, b0, s0, t0, h0);
    hipLaunchKernelGGL((gemm_relu_kernel<64>), dim3(512), dim3(256), 0, stream, h0, Wp1, bias1, h1);
    hipLaunchKernelGGL((gemm_relu_kernel<128>), dim3(512), dim3(256), 0, stream, h1, Wp2, bias2, h2);
    hipLaunchKernelGGL(gemm3_max_kernel, dim3(1024), dim3(256), 0, stream, h2, Wp3, bias3, out);
}